// Round 4
// baseline (3910.369 us; speedup 1.0000x reference)
//
#include <hip/hip_runtime.h>
#include <hip/hip_bf16.h>

typedef __hip_bfloat16 bf16;
typedef float f32x4 __attribute__((ext_vector_type(4)));
typedef __bf16 b16x8 __attribute__((ext_vector_type(8)));

constexpr int Lc = 12, Bc = 4, Nc = 512, Dc = 768, Hc = 12, DHc = 64, DFFc = 3072;
constexpr int QKVc = 3 * Dc;          // 2304
constexpr int Mrows = Bc * Nc;        // 2048
constexpr float SCALE = 0.125f;       // 1/sqrt(64)

__device__ __forceinline__ bf16 f2b(float x) { return __float2bfloat16(x); }

__device__ __forceinline__ void mfma_bf16(f32x4& d, b16x8 a, b16x8 b) {
  d = __builtin_amdgcn_mfma_f32_16x16x32_bf16(a, b, d, 0, 0, 0);
}

// ---------------------------------------------------------------------------
// Generic GEMM:  C[m][n] = sum_k A[m][k] * Bt[n][k]   (A, Bt bf16 row-major)
// MODE 0: outb = bf16(C)                      (qkv projection, no bias)
// MODE 1: outb = bf16(gelu(C + bias))         (ff1)
// MODE 2: xres += C + bias                    (o-proj, ff2 residual, fp32)
// MODE 3: outf = C * SCALE, per-(b,h) ptrs    (attention scores -> d_out fp32)
// MODE 4: outb = bf16(C), per-(b,h) ptrs      (PV, A = bf16 attn copy)
// ---------------------------------------------------------------------------
template <int BM, int BN, int WM, int WN, int MODE>
__global__ __launch_bounds__(256) void gemm_bt(
    const bf16* __restrict__ Abase, const bf16* __restrict__ Btbase,
    const float* __restrict__ bias, float* __restrict__ xres,
    bf16* __restrict__ outb_, float* __restrict__ outf_,
    int M, int N, int K, int lda, int ldb, int ldc) {
  constexpr int MI = WM / 16, NI = WN / 16;
  constexpr int NWN = BN / WN;
  const int tid = threadIdx.x;
  const int lane = tid & 63, wave = tid >> 6;
  const int wm = (wave / NWN) * WM, wn = (wave % NWN) * WN;
  const int tm0 = blockIdx.x * BM, tn0 = blockIdx.y * BN;
  const int z = blockIdx.z;

  const bf16* A = Abase;
  const bf16* Bt = Btbase;
  bf16* outb = outb_;
  float* outf = outf_;

  if (MODE == 3) {
    size_t off = (size_t)(z / Hc) * Nc * QKVc + (size_t)(z % Hc) * DHc;
    A = Abase + off;            // Q block, lda = 2304
    Bt = Abase + off + Dc;      // K block, ldb = 2304
    outf = outf_ + (size_t)z * Nc * Nc;       // fp32 scores into d_out
  } else if (MODE == 4) {
    A = Abase + (size_t)z * Nc * Nc;          // bf16 attn copy (ws)
    Bt = Btbase + (size_t)z * DHc * Nc;       // V^T per (b,h)
    outb = outb_ + (size_t)(z / Hc) * Nc * Dc + (size_t)(z % Hc) * DHc;
  }

  __shared__ __align__(16) bf16 As[BM * 32];
  __shared__ __align__(16) bf16 Bs[BN * 32];

  f32x4 acc[MI][NI] = {};

  for (int k0 = 0; k0 < K; k0 += 32) {
    #pragma unroll
    for (int e = tid * 8; e < BM * 32; e += 256 * 8) {
      int r = e >> 5, kk = e & 31;
      *(uint4*)(As + e) = *(const uint4*)(A + (size_t)(tm0 + r) * lda + (k0 + kk));
    }
    #pragma unroll
    for (int e = tid * 8; e < BN * 32; e += 256 * 8) {
      int r = e >> 5, kk = e & 31;
      *(uint4*)(Bs + e) = *(const uint4*)(Bt + (size_t)(tn0 + r) * ldb + (k0 + kk));
    }
    __syncthreads();

    b16x8 af[MI], bfr[NI];
    #pragma unroll
    for (int i = 0; i < MI; i++)
      af[i] = *(const b16x8*)(As + (wm + i * 16 + (lane & 15)) * 32 + (lane >> 4) * 8);
    #pragma unroll
    for (int j = 0; j < NI; j++)
      bfr[j] = *(const b16x8*)(Bs + (wn + j * 16 + (lane & 15)) * 32 + (lane >> 4) * 8);
    #pragma unroll
    for (int i = 0; i < MI; i++)
      #pragma unroll
      for (int j = 0; j < NI; j++)
        mfma_bf16(acc[i][j], af[i], bfr[j]);
    __syncthreads();
  }

  // epilogue: D mapping col = lane&15, row = (lane>>4)*4 + reg
  const int r0 = (lane >> 4) * 4;
  const int c0 = lane & 15;
  #pragma unroll
  for (int i = 0; i < MI; i++) {
    #pragma unroll
    for (int j = 0; j < NI; j++) {
      #pragma unroll
      for (int r = 0; r < 4; r++) {
        int row = tm0 + wm + i * 16 + r0 + r;
        int col = tn0 + wn + j * 16 + c0;
        float v = acc[i][j][r];
        if (MODE == 0) {
          outb[(size_t)row * ldc + col] = f2b(v);
        } else if (MODE == 1) {
          v += bias[col];
          float g = 0.5f * v * (1.0f + erff(v * 0.70710678118654752f));
          outb[(size_t)row * ldc + col] = f2b(g);
        } else if (MODE == 2) {
          v += bias[col];
          xres[(size_t)row * ldc + col] += v;
        } else if (MODE == 3) {
          outf[(size_t)row * ldc + col] = v * SCALE;
        } else {  // MODE 4
          outb[(size_t)row * ldc + col] = f2b(v);
        }
      }
    }
  }
}

// ---------------------------------------------------------------------------
// LayerNorm: per row of 768, fp32 in -> bf16 out
// ---------------------------------------------------------------------------
__global__ __launch_bounds__(256) void ln_k(const float* __restrict__ x,
                                            const float* __restrict__ s,
                                            const float* __restrict__ b,
                                            bf16* __restrict__ out) {
  const int row = blockIdx.x, tid = threadIdx.x;
  const float* xr = x + (size_t)row * Dc;
  float a0 = xr[tid], a1 = xr[tid + 256], a2 = xr[tid + 512];
  float sum = a0 + a1 + a2;
  float sq = a0 * a0 + a1 * a1 + a2 * a2;
  #pragma unroll
  for (int o = 32; o; o >>= 1) {
    sum += __shfl_down(sum, o);
    sq += __shfl_down(sq, o);
  }
  __shared__ float s1[4], s2[4];
  if ((tid & 63) == 0) { s1[tid >> 6] = sum; s2[tid >> 6] = sq; }
  __syncthreads();
  sum = s1[0] + s1[1] + s1[2] + s1[3];
  sq = s2[0] + s2[1] + s2[2] + s2[3];
  float m = sum * (1.0f / Dc);
  float var = sq * (1.0f / Dc) - m * m;
  float rs = rsqrtf(var + 1e-5f);
  bf16* orow = out + (size_t)row * Dc;
  orow[tid]       = f2b((a0 - m) * rs * s[tid]       + b[tid]);
  orow[tid + 256] = f2b((a1 - m) * rs * s[tid + 256] + b[tid + 256]);
  orow[tid + 512] = f2b((a2 - m) * rs * s[tid + 512] + b[tid + 512]);
}

// ---------------------------------------------------------------------------
// Softmax over rows of 512 fp32 scores (in d_out), in-place fp32 result +
// bf16 side copy for the PV GEMM.
// ---------------------------------------------------------------------------
__global__ __launch_bounds__(256) void sm_k(float* __restrict__ sc,
                                            bf16* __restrict__ at) {
  const size_t base = (size_t)blockIdx.x * Nc;
  const int tid = threadIdx.x;
  float a0 = sc[base + tid], a1 = sc[base + tid + 256];
  float mx = fmaxf(a0, a1);
  #pragma unroll
  for (int o = 32; o; o >>= 1) mx = fmaxf(mx, __shfl_down(mx, o));
  __shared__ float r1[4], r2[4];
  if ((tid & 63) == 0) r1[tid >> 6] = mx;
  __syncthreads();
  mx = fmaxf(fmaxf(r1[0], r1[1]), fmaxf(r1[2], r1[3]));
  float e0 = expf(a0 - mx), e1 = expf(a1 - mx);
  float sum = e0 + e1;
  #pragma unroll
  for (int o = 32; o; o >>= 1) sum += __shfl_down(sum, o);
  if ((tid & 63) == 0) r2[tid >> 6] = sum;
  __syncthreads();
  sum = r2[0] + r2[1] + r2[2] + r2[3];
  float rcp = 1.0f / sum;
  float p0 = e0 * rcp, p1 = e1 * rcp;
  sc[base + tid] = p0;
  sc[base + tid + 256] = p1;
  at[base + tid] = f2b(p0);
  at[base + tid + 256] = f2b(p1);
}

// ---------------------------------------------------------------------------
// Weight transpose + fp32->bf16:  out[n][k] = bf16(in[k][n]); dims % 64 == 0
// ---------------------------------------------------------------------------
__global__ __launch_bounds__(256) void twb_k(const float* __restrict__ in,
                                             bf16* __restrict__ out, int K, int Nw) {
  const int n0 = blockIdx.x * 64, k0 = blockIdx.y * 64;
  __shared__ bf16 t[64][65];
  const int tx = threadIdx.x & 63, ty = threadIdx.x >> 6;
  #pragma unroll
  for (int kk = ty; kk < 64; kk += 4)
    t[tx][kk] = f2b(in[(size_t)(k0 + kk) * Nw + n0 + tx]);
  __syncthreads();
  #pragma unroll
  for (int nn = ty; nn < 64; nn += 4)
    out[(size_t)(n0 + nn) * K + k0 + tx] = t[nn][tx];
}

// ---------------------------------------------------------------------------
// V transpose: vt[(b*H+h)*64 + d][n] = qkv[(b*512+n)][1536 + h*64 + d]
// ---------------------------------------------------------------------------
__global__ __launch_bounds__(256) void vtrans_k(const bf16* __restrict__ qkv,
                                                bf16* __restrict__ vt) {
  const int bh = blockIdx.z;
  const int b = bh / Hc, h = bh % Hc;
  const int n0 = blockIdx.x * 64;
  const bf16* src = qkv + (size_t)b * Nc * QKVc + 2 * Dc + h * DHc;
  __shared__ bf16 t[64][65];
  const int tx = threadIdx.x & 63, ty = threadIdx.x >> 6;
  #pragma unroll
  for (int nn = ty; nn < 64; nn += 4)
    t[tx][nn] = src[(size_t)(n0 + nn) * QKVc + tx];
  __syncthreads();
  bf16* dst = vt + (size_t)bh * DHc * Nc;
  #pragma unroll
  for (int dd = ty; dd < 64; dd += 4)
    dst[(size_t)dd * Nc + n0 + tx] = t[dd][tx];
}

// ---------------------------------------------------------------------------
extern "C" void kernel_launch(void* const* d_in, const int* in_sizes, int n_in,
                              void* d_out, int out_size, void* d_ws, size_t ws_size,
                              hipStream_t stream) {
  const float* x_in  = (const float*)d_in[0];
  const float* ln1_s = (const float*)d_in[1];
  const float* ln1_b = (const float*)d_in[2];
  const float* wqkv  = (const float*)d_in[3];
  const float* wo    = (const float*)d_in[4];
  const float* bo    = (const float*)d_in[5];
  const float* ln2_s = (const float*)d_in[6];
  const float* ln2_b = (const float*)d_in[7];
  const float* w1    = (const float*)d_in[8];
  const float* b1    = (const float*)d_in[9];
  const float* w2    = (const float*)d_in[10];
  const float* b2    = (const float*)d_in[11];
  float* out = (float*)d_out;   // fp32! (reference outputs are float32)

  // workspace carve-up (bytes)
  char* ws = (char*)d_ws;
  float* x      = (float*)(ws + 0);          //  6,291,456  fp32 [2048][768]
  bf16* h       = (bf16*)(ws + 6291456);     //  3,145,728  bf16 [2048][768]
  bf16* qkv     = (bf16*)(ws + 9437184);     //  9,437,184  bf16 [2048][2304]
  bf16* o       = (bf16*)(ws + 18874368);    //  3,145,728  bf16 [2048][768]
  bf16* ff      = (bf16*)(ws + 22020096);    // 12,582,912  bf16 [2048][3072]
  bf16* vt      = (bf16*)(ws + 34603008);    //  3,145,728  bf16 [48][64][512]
  bf16* wT      = (bf16*)(ws + 37748736);    //  4,718,592  bf16 (max of the 4 W^T)
  bf16* attn_bf = (bf16*)(ws + 42467328);    // 25,165,824  bf16 [48][512][512]
  if (ws_size < (size_t)67633152) return;

  hipMemcpyAsync(x, x_in, (size_t)Mrows * Dc * sizeof(float),
                 hipMemcpyDeviceToDevice, stream);

  constexpr size_t ATTN_BASE = (size_t)Mrows * Dc;           // 1,572,864 floats
  constexpr size_t ATTN_L = (size_t)Bc * Hc * Nc * Nc;       // 12,582,912 floats

  for (int l = 0; l < Lc; l++) {
    float* attn_l = out + ATTN_BASE + (size_t)l * ATTN_L;    // fp32 slice

    // --- attention ---
    twb_k<<<dim3(QKVc / 64, Dc / 64), 256, 0, stream>>>(
        wqkv + (size_t)l * Dc * QKVc, wT, Dc, QKVc);
    ln_k<<<Mrows, 256, 0, stream>>>(x, ln1_s + l * Dc, ln1_b + l * Dc, h);
    gemm_bt<128, 128, 64, 64, 0><<<dim3(Mrows / 128, QKVc / 128, 1), 256, 0, stream>>>(
        h, wT, nullptr, nullptr, qkv, nullptr, Mrows, QKVc, Dc, Dc, Dc, QKVc);
    vtrans_k<<<dim3(Nc / 64, 1, Bc * Hc), 256, 0, stream>>>(qkv, vt);
    // QK^T -> fp32 scores straight into d_out
    gemm_bt<128, 128, 64, 64, 3><<<dim3(Nc / 128, Nc / 128, Bc * Hc), 256, 0, stream>>>(
        qkv, nullptr, nullptr, nullptr, nullptr, attn_l, Nc, Nc, DHc, QKVc, QKVc, Nc);
    // softmax in-place (fp32) + bf16 copy for PV
    sm_k<<<Bc * Hc * Nc, 256, 0, stream>>>(attn_l, attn_bf);
    gemm_bt<128, 64, 64, 32, 4><<<dim3(Nc / 128, 1, Bc * Hc), 256, 0, stream>>>(
        attn_bf, vt, nullptr, nullptr, o, nullptr, Nc, DHc, Nc, Nc, Nc, Dc);
    twb_k<<<dim3(Dc / 64, Dc / 64), 256, 0, stream>>>(
        wo + (size_t)l * Dc * Dc, wT, Dc, Dc);
    gemm_bt<128, 128, 64, 64, 2><<<dim3(Mrows / 128, Dc / 128, 1), 256, 0, stream>>>(
        o, wT, bo + l * Dc, x, nullptr, nullptr, Mrows, Dc, Dc, Dc, Dc, Dc);

    // --- feed-forward ---
    ln_k<<<Mrows, 256, 0, stream>>>(x, ln2_s + l * Dc, ln2_b + l * Dc, h);
    twb_k<<<dim3(DFFc / 64, Dc / 64), 256, 0, stream>>>(
        w1 + (size_t)l * Dc * DFFc, wT, Dc, DFFc);
    gemm_bt<128, 128, 64, 64, 1><<<dim3(Mrows / 128, DFFc / 128, 1), 256, 0, stream>>>(
        h, wT, b1 + l * DFFc, nullptr, ff, nullptr, Mrows, DFFc, Dc, Dc, Dc, DFFc);
    twb_k<<<dim3(Dc / 64, DFFc / 64), 256, 0, stream>>>(
        w2 + (size_t)l * DFFc * Dc, wT, DFFc, Dc);
    gemm_bt<128, 128, 64, 64, 2><<<dim3(Mrows / 128, Dc / 128, 1), 256, 0, stream>>>(
        ff, wT, b2 + l * Dc, x, nullptr, nullptr, Mrows, Dc, DFFc, DFFc, DFFc, Dc);
  }

  // final residual stream -> d_out (fp32)
  hipMemcpyAsync(out, x, (size_t)Mrows * Dc * sizeof(float),
                 hipMemcpyDeviceToDevice, stream);
}

// Round 5
// 3095.734 us; speedup vs baseline: 1.2631x; 1.2631x over previous
//
#include <hip/hip_runtime.h>
#include <hip/hip_bf16.h>

typedef __hip_bfloat16 bf16;
typedef float f32x4 __attribute__((ext_vector_type(4)));
typedef __bf16 b16x8 __attribute__((ext_vector_type(8)));

constexpr int Lc = 12, Bc = 4, Nc = 512, Dc = 768, Hc = 12, DHc = 64, DFFc = 3072;
constexpr int QKVc = 3 * Dc;          // 2304
constexpr int Mrows = Bc * Nc;        // 2048
constexpr float SCALE = 0.125f;       // 1/sqrt(64)

__device__ __forceinline__ bf16 f2b(float x) { return __float2bfloat16(x); }

__device__ __forceinline__ void mfma_bf16(f32x4& d, b16x8 a, b16x8 b) {
  d = __builtin_amdgcn_mfma_f32_16x16x32_bf16(a, b, d, 0, 0, 0);
}

// async global->LDS, 16B per lane. LDS dest must be linear (wave base + lane*16).
__device__ __forceinline__ void gload16(const bf16* g, bf16* l) {
  __builtin_amdgcn_global_load_lds(
      (const __attribute__((address_space(1))) void*)g,
      (__attribute__((address_space(3))) void*)l, 16, 0, 0);
}

// ---------------------------------------------------------------------------
// Generic GEMM:  C[m][n] = sum_k A[m][k] * Bt[n][k]   (A, Bt bf16 row-major)
// MODE 0: outb = bf16(C)                      (qkv projection, no bias)
// MODE 1: outb = bf16(gelu(C + bias))         (ff1)
// MODE 2: xres += C + bias                    (o-proj, ff2 residual, fp32)
// MODE 4: outb = bf16(C), per-(b,h) ptrs      (PV, A = bf16 attn copy)
// ---------------------------------------------------------------------------
template <int BM, int BN, int WM, int WN, int MODE>
__global__ __launch_bounds__(256) void gemm_bt(
    const bf16* __restrict__ Abase, const bf16* __restrict__ Btbase,
    const float* __restrict__ bias, float* __restrict__ xres,
    bf16* __restrict__ outb_,
    int M, int N, int K, int lda, int ldb, int ldc) {
  constexpr int MI = WM / 16, NI = WN / 16;
  constexpr int NWN = BN / WN;
  const int tid = threadIdx.x;
  const int lane = tid & 63, wave = tid >> 6;
  const int wm = (wave / NWN) * WM, wn = (wave % NWN) * WN;
  const int tm0 = blockIdx.x * BM, tn0 = blockIdx.y * BN;
  const int z = blockIdx.z;

  const bf16* A = Abase;
  const bf16* Bt = Btbase;
  bf16* outb = outb_;

  if (MODE == 4) {
    A = Abase + (size_t)z * Nc * Nc;          // bf16 attn copy (ws)
    Bt = Btbase + (size_t)z * DHc * Nc;       // V^T per (b,h)
    outb = outb_ + (size_t)(z / Hc) * Nc * Dc + (size_t)(z % Hc) * DHc;
  }

  __shared__ __align__(16) bf16 As[BM * 32];
  __shared__ __align__(16) bf16 Bs[BN * 32];

  f32x4 acc[MI][NI] = {};

  for (int k0 = 0; k0 < K; k0 += 32) {
    // async-stage A/B tiles: 16B per lane, linear LDS
    #pragma unroll
    for (int rr = 0; rr < BM / 64; rr++) {
      int e = rr * 2048 + tid * 8;
      int r = e >> 5, kk = e & 31;
      gload16(A + (size_t)(tm0 + r) * lda + (k0 + kk), As + e);
    }
    #pragma unroll
    for (int rr = 0; rr < BN / 64; rr++) {
      int e = rr * 2048 + tid * 8;
      int r = e >> 5, kk = e & 31;
      gload16(Bt + (size_t)(tn0 + r) * ldb + (k0 + kk), Bs + e);
    }
    __syncthreads();  // drains vmcnt (loads-to-LDS complete)

    b16x8 af[MI], bfr[NI];
    #pragma unroll
    for (int i = 0; i < MI; i++)
      af[i] = *(const b16x8*)(As + (wm + i * 16 + (lane & 15)) * 32 + (lane >> 4) * 8);
    #pragma unroll
    for (int j = 0; j < NI; j++)
      bfr[j] = *(const b16x8*)(Bs + (wn + j * 16 + (lane & 15)) * 32 + (lane >> 4) * 8);
    #pragma unroll
    for (int i = 0; i < MI; i++)
      #pragma unroll
      for (int j = 0; j < NI; j++)
        mfma_bf16(acc[i][j], af[i], bfr[j]);
    __syncthreads();
  }

  // epilogue: D mapping col = lane&15, row = (lane>>4)*4 + reg
  const int r0 = (lane >> 4) * 4;
  const int c0 = lane & 15;
  #pragma unroll
  for (int i = 0; i < MI; i++) {
    #pragma unroll
    for (int j = 0; j < NI; j++) {
      #pragma unroll
      for (int r = 0; r < 4; r++) {
        int row = tm0 + wm + i * 16 + r0 + r;
        int col = tn0 + wn + j * 16 + c0;
        float v = acc[i][j][r];
        if (MODE == 0) {
          outb[(size_t)row * ldc + col] = f2b(v);
        } else if (MODE == 1) {
          v += bias[col];
          float g = 0.5f * v * (1.0f + erff(v * 0.70710678118654752f));
          outb[(size_t)row * ldc + col] = f2b(g);
        } else if (MODE == 2) {
          v += bias[col];
          xres[(size_t)row * ldc + col] += v;
        } else {  // MODE 4
          outb[(size_t)row * ldc + col] = f2b(v);
        }
      }
    }
  }
}

// ---------------------------------------------------------------------------
// Fused QK^T * SCALE -> softmax. One block = 32 q-rows x all 512 kv for one
// (b,h). K-head staged once in LDS (padded rows: kills 128B-stride bank
// conflicts). Softmax entirely in-register on the MFMA accumulators.
// Writes fp32 attn to d_out and bf16 copy for the PV GEMM.
// ---------------------------------------------------------------------------
__global__ __launch_bounds__(256) void qksm_k(const bf16* __restrict__ qkv,
                                              float* __restrict__ attn_f,
                                              bf16* __restrict__ attn_b) {
  const int bh = blockIdx.y;
  const int b = bh / Hc, h = bh % Hc;
  const int n0 = blockIdx.x * 32;
  const int tid = threadIdx.x, lane = tid & 63, wave = tid >> 6;
  const int wn = wave * 128;

  constexpr int KP = 72;  // 64 + 8 pad (bank-conflict break, keeps 16B align)
  __shared__ __align__(16) bf16 Ks[512 * KP];
  __shared__ float red[32][4];

  const bf16* qbase = qkv + (size_t)b * Nc * QKVc + h * DHc;  // Q cols
  const bf16* kbase = qbase + Dc;                             // K cols

  // stage whole K-head: 512 rows x 64 cols (16 rounds of 4KB)
  for (int e = tid * 8; e < 512 * 64; e += 256 * 8) {
    int kv = e >> 6, c = e & 63;
    *(uint4*)(Ks + kv * KP + c) = *(const uint4*)(kbase + (size_t)kv * QKVc + c);
  }
  // Q fragments direct from global
  b16x8 qf[2][2];  // [ks][i]
  #pragma unroll
  for (int ks = 0; ks < 2; ks++)
    #pragma unroll
    for (int i = 0; i < 2; i++)
      qf[ks][i] = *(const b16x8*)(qbase +
          (size_t)(n0 + i * 16 + (lane & 15)) * QKVc + ks * 32 + (lane >> 4) * 8);
  __syncthreads();

  f32x4 acc[2][8] = {};  // [i(row16)][j(col16)]
  #pragma unroll
  for (int ks = 0; ks < 2; ks++) {
    #pragma unroll
    for (int j = 0; j < 8; j++) {
      b16x8 kf = *(const b16x8*)(Ks + (wn + j * 16 + (lane & 15)) * KP +
                                 ks * 32 + (lane >> 4) * 8);
      #pragma unroll
      for (int i = 0; i < 2; i++)
        mfma_bf16(acc[i][j], qf[ks][i], kf);
    }
  }

  // scale
  #pragma unroll
  for (int i = 0; i < 2; i++)
    #pragma unroll
    for (int j = 0; j < 8; j++)
      acc[i][j] *= SCALE;

  const int r0 = (lane >> 4) * 4, c0 = lane & 15;
  float rmax[2][4];
  // row max: over j regs, then over the 16-lane col group, then 4 waves
  #pragma unroll
  for (int i = 0; i < 2; i++)
    #pragma unroll
    for (int rr = 0; rr < 4; rr++) {
      float m = -1e30f;
      #pragma unroll
      for (int j = 0; j < 8; j++) m = fmaxf(m, acc[i][j][rr]);
      #pragma unroll
      for (int o = 1; o < 16; o <<= 1) m = fmaxf(m, __shfl_xor(m, o));
      rmax[i][rr] = m;
    }
  if (c0 == 0) {
    #pragma unroll
    for (int i = 0; i < 2; i++)
      #pragma unroll
      for (int rr = 0; rr < 4; rr++)
        red[i * 16 + r0 + rr][wave] = rmax[i][rr];
  }
  __syncthreads();
  #pragma unroll
  for (int i = 0; i < 2; i++)
    #pragma unroll
    for (int rr = 0; rr < 4; rr++) {
      int r = i * 16 + r0 + rr;
      rmax[i][rr] = fmaxf(fmaxf(red[r][0], red[r][1]), fmaxf(red[r][2], red[r][3]));
    }
  __syncthreads();  // red reused for sums

  float rsum[2][4];
  #pragma unroll
  for (int i = 0; i < 2; i++)
    #pragma unroll
    for (int rr = 0; rr < 4; rr++) {
      float s = 0.f;
      #pragma unroll
      for (int j = 0; j < 8; j++) {
        float e = expf(acc[i][j][rr] - rmax[i][rr]);
        acc[i][j][rr] = e;
        s += e;
      }
      #pragma unroll
      for (int o = 1; o < 16; o <<= 1) s += __shfl_xor(s, o);
      rsum[i][rr] = s;
    }
  if (c0 == 0) {
    #pragma unroll
    for (int i = 0; i < 2; i++)
      #pragma unroll
      for (int rr = 0; rr < 4; rr++)
        red[i * 16 + r0 + rr][wave] = rsum[i][rr];
  }
  __syncthreads();
  #pragma unroll
  for (int i = 0; i < 2; i++)
    #pragma unroll
    for (int rr = 0; rr < 4; rr++) {
      int r = i * 16 + r0 + rr;
      rsum[i][rr] = 1.0f / (red[r][0] + red[r][1] + red[r][2] + red[r][3]);
    }

  float* of = attn_f + (size_t)bh * Nc * Nc;
  bf16*  ob = attn_b + (size_t)bh * Nc * Nc;
  #pragma unroll
  for (int i = 0; i < 2; i++)
    #pragma unroll
    for (int j = 0; j < 8; j++)
      #pragma unroll
      for (int rr = 0; rr < 4; rr++) {
        int row = n0 + i * 16 + r0 + rr;
        int col = wn + j * 16 + c0;
        float p = acc[i][j][rr] * rsum[i][rr];
        of[(size_t)row * Nc + col] = p;
        ob[(size_t)row * Nc + col] = f2b(p);
      }
}

// ---------------------------------------------------------------------------
// LayerNorm: per row of 768, fp32 in -> bf16 out
// ---------------------------------------------------------------------------
__global__ __launch_bounds__(256) void ln_k(const float* __restrict__ x,
                                            const float* __restrict__ s,
                                            const float* __restrict__ b,
                                            bf16* __restrict__ out) {
  const int row = blockIdx.x, tid = threadIdx.x;
  const float* xr = x + (size_t)row * Dc;
  float a0 = xr[tid], a1 = xr[tid + 256], a2 = xr[tid + 512];
  float sum = a0 + a1 + a2;
  float sq = a0 * a0 + a1 * a1 + a2 * a2;
  #pragma unroll
  for (int o = 32; o; o >>= 1) {
    sum += __shfl_down(sum, o);
    sq += __shfl_down(sq, o);
  }
  __shared__ float s1[4], s2[4];
  if ((tid & 63) == 0) { s1[tid >> 6] = sum; s2[tid >> 6] = sq; }
  __syncthreads();
  sum = s1[0] + s1[1] + s1[2] + s1[3];
  sq = s2[0] + s2[1] + s2[2] + s2[3];
  float m = sum * (1.0f / Dc);
  float var = sq * (1.0f / Dc) - m * m;
  float rs = rsqrtf(var + 1e-5f);
  bf16* orow = out + (size_t)row * Dc;
  orow[tid]       = f2b((a0 - m) * rs * s[tid]       + b[tid]);
  orow[tid + 256] = f2b((a1 - m) * rs * s[tid + 256] + b[tid + 256]);
  orow[tid + 512] = f2b((a2 - m) * rs * s[tid + 512] + b[tid + 512]);
}

// ---------------------------------------------------------------------------
// Weight transpose + fp32->bf16:  out[n][k] = bf16(in[k][n]); dims % 64 == 0
// ---------------------------------------------------------------------------
__global__ __launch_bounds__(256) void twb_k(const float* __restrict__ in,
                                             bf16* __restrict__ out, int K, int Nw) {
  const int n0 = blockIdx.x * 64, k0 = blockIdx.y * 64;
  __shared__ bf16 t[64][65];
  const int tx = threadIdx.x & 63, ty = threadIdx.x >> 6;
  #pragma unroll
  for (int kk = ty; kk < 64; kk += 4)
    t[tx][kk] = f2b(in[(size_t)(k0 + kk) * Nw + n0 + tx]);
  __syncthreads();
  #pragma unroll
  for (int nn = ty; nn < 64; nn += 4)
    out[(size_t)(n0 + nn) * K + k0 + tx] = t[nn][tx];
}

// ---------------------------------------------------------------------------
// V transpose: vt[(b*H+h)*64 + d][n] = qkv[(b*512+n)][1536 + h*64 + d]
// ---------------------------------------------------------------------------
__global__ __launch_bounds__(256) void vtrans_k(const bf16* __restrict__ qkv,
                                                bf16* __restrict__ vt) {
  const int bh = blockIdx.z;
  const int b = bh / Hc, h = bh % Hc;
  const int n0 = blockIdx.x * 64;
  const bf16* src = qkv + (size_t)b * Nc * QKVc + 2 * Dc + h * DHc;
  __shared__ bf16 t[64][65];
  const int tx = threadIdx.x & 63, ty = threadIdx.x >> 6;
  #pragma unroll
  for (int nn = ty; nn < 64; nn += 4)
    t[tx][nn] = src[(size_t)(n0 + nn) * QKVc + tx];
  __syncthreads();
  bf16* dst = vt + (size_t)bh * DHc * Nc;
  #pragma unroll
  for (int dd = ty; dd < 64; dd += 4)
    dst[(size_t)dd * Nc + n0 + tx] = t[dd][tx];
}

// ---------------------------------------------------------------------------
extern "C" void kernel_launch(void* const* d_in, const int* in_sizes, int n_in,
                              void* d_out, int out_size, void* d_ws, size_t ws_size,
                              hipStream_t stream) {
  const float* x_in  = (const float*)d_in[0];
  const float* ln1_s = (const float*)d_in[1];
  const float* ln1_b = (const float*)d_in[2];
  const float* wqkv  = (const float*)d_in[3];
  const float* wo    = (const float*)d_in[4];
  const float* bo    = (const float*)d_in[5];
  const float* ln2_s = (const float*)d_in[6];
  const float* ln2_b = (const float*)d_in[7];
  const float* w1    = (const float*)d_in[8];
  const float* b1    = (const float*)d_in[9];
  const float* w2    = (const float*)d_in[10];
  const float* b2    = (const float*)d_in[11];
  float* out = (float*)d_out;   // fp32 (reference outputs are float32)

  // workspace carve-up (bytes)
  char* ws = (char*)d_ws;
  float* x      = (float*)(ws + 0);          //  6,291,456  fp32 [2048][768]
  bf16* h       = (bf16*)(ws + 6291456);     //  3,145,728  bf16 [2048][768]
  bf16* qkv     = (bf16*)(ws + 9437184);     //  9,437,184  bf16 [2048][2304]
  bf16* o       = (bf16*)(ws + 18874368);    //  3,145,728  bf16 [2048][768]
  bf16* ff      = (bf16*)(ws + 22020096);    // 12,582,912  bf16 [2048][3072]
  bf16* vt      = (bf16*)(ws + 34603008);    //  3,145,728  bf16 [48][64][512]
  bf16* wT      = (bf16*)(ws + 37748736);    //  4,718,592  bf16 (max of the 4 W^T)
  bf16* attn_bf = (bf16*)(ws + 42467328);    // 25,165,824  bf16 [48][512][512]
  if (ws_size < (size_t)67633152) return;

  hipMemcpyAsync(x, x_in, (size_t)Mrows * Dc * sizeof(float),
                 hipMemcpyDeviceToDevice, stream);

  constexpr size_t ATTN_BASE = (size_t)Mrows * Dc;           // floats
  constexpr size_t ATTN_L = (size_t)Bc * Hc * Nc * Nc;       // floats

  for (int l = 0; l < Lc; l++) {
    float* attn_l = out + ATTN_BASE + (size_t)l * ATTN_L;    // fp32 slice

    // --- attention ---
    twb_k<<<dim3(QKVc / 64, Dc / 64), 256, 0, stream>>>(
        wqkv + (size_t)l * Dc * QKVc, wT, Dc, QKVc);
    ln_k<<<Mrows, 256, 0, stream>>>(x, ln1_s + l * Dc, ln1_b + l * Dc, h);
    gemm_bt<128, 128, 64, 64, 0><<<dim3(Mrows / 128, QKVc / 128, 1), 256, 0, stream>>>(
        h, wT, nullptr, nullptr, qkv, Mrows, QKVc, Dc, Dc, Dc, QKVc);
    vtrans_k<<<dim3(Nc / 64, 1, Bc * Hc), 256, 0, stream>>>(qkv, vt);
    // fused QK^T*scale + softmax -> fp32 attn (d_out) + bf16 copy (ws)
    qksm_k<<<dim3(Nc / 32, Bc * Hc), 256, 0, stream>>>(qkv, attn_l, attn_bf);
    gemm_bt<128, 64, 64, 32, 4><<<dim3(Nc / 128, 1, Bc * Hc), 256, 0, stream>>>(
        attn_bf, vt, nullptr, nullptr, o, Nc, DHc, Nc, Nc, Nc, Dc);
    twb_k<<<dim3(Dc / 64, Dc / 64), 256, 0, stream>>>(
        wo + (size_t)l * Dc * Dc, wT, Dc, Dc);
    gemm_bt<128, 128, 64, 64, 2><<<dim3(Mrows / 128, Dc / 128, 1), 256, 0, stream>>>(
        o, wT, bo + l * Dc, x, nullptr, Mrows, Dc, Dc, Dc, Dc, Dc);

    // --- feed-forward ---
    ln_k<<<Mrows, 256, 0, stream>>>(x, ln2_s + l * Dc, ln2_b + l * Dc, h);
    twb_k<<<dim3(DFFc / 64, Dc / 64), 256, 0, stream>>>(
        w1 + (size_t)l * Dc * DFFc, wT, Dc, DFFc);
    gemm_bt<128, 128, 64, 64, 1><<<dim3(Mrows / 128, DFFc / 128, 1), 256, 0, stream>>>(
        h, wT, b1 + l * DFFc, nullptr, ff, Mrows, DFFc, Dc, Dc, Dc, DFFc);
    twb_k<<<dim3(Dc / 64, DFFc / 64), 256, 0, stream>>>(
        w2 + (size_t)l * DFFc * Dc, wT, DFFc, Dc);
    gemm_bt<128, 128, 64, 64, 2><<<dim3(Mrows / 128, Dc / 128, 1), 256, 0, stream>>>(
        ff, wT, b2 + l * Dc, x, nullptr, Mrows, Dc, DFFc, DFFc, DFFc, Dc);
  }

  // final residual stream -> d_out (fp32)
  hipMemcpyAsync(out, x, (size_t)Mrows * Dc * sizeof(float),
                 hipMemcpyDeviceToDevice, stream);
}

// Round 6
// 2496.570 us; speedup vs baseline: 1.5663x; 1.2400x over previous
//
#include <hip/hip_runtime.h>
#include <hip/hip_bf16.h>

typedef __hip_bfloat16 bf16;
typedef float f32x4 __attribute__((ext_vector_type(4)));
typedef __bf16 b16x8 __attribute__((ext_vector_type(8)));

constexpr int Lc = 12, Bc = 4, Nc = 512, Dc = 768, Hc = 12, DHc = 64, DFFc = 3072;
constexpr int QKVc = 3 * Dc;          // 2304
constexpr int Mrows = Bc * Nc;        // 2048
constexpr float SCALE = 0.125f;       // 1/sqrt(64)

__device__ __forceinline__ bf16 f2b(float x) { return __float2bfloat16(x); }

__device__ __forceinline__ void mfma_bf16(f32x4& d, b16x8 a, b16x8 b) {
  d = __builtin_amdgcn_mfma_f32_16x16x32_bf16(a, b, d, 0, 0, 0);
}

// async global->LDS, 16B per lane. LDS dest must be linear (wave base + lane*16).
__device__ __forceinline__ void gload16(const bf16* g, bf16* l) {
  __builtin_amdgcn_global_load_lds(
      (const __attribute__((address_space(1))) void*)g,
      (__attribute__((address_space(3))) void*)l, 16, 0, 0);
}

// ---------------------------------------------------------------------------
// Generic GEMM:  C[m][n] = sum_k A[m][k] * Bt[n][k]   (A, Bt bf16 row-major)
// 2-phase double-buffered K-loop: prefetch tile t+1 (global_load_lds) is
// issued BEFORE computing tile t; one __syncthreads per step (its vmcnt(0)
// drain lands after compute has covered the load latency).
// MODE 0: outb = bf16(C)                      (qkv projection, no bias)
// MODE 1: outb = bf16(gelu(C + bias))         (ff1)
// MODE 2: xres += C + bias                    (o-proj, ff2 residual, fp32)
// MODE 4: outb = bf16(C), per-(b,h) ptrs      (PV, A = bf16 attn copy)
// ---------------------------------------------------------------------------
template <int BM, int BN, int WM, int WN, int MODE>
__global__ __launch_bounds__(256) void gemm_bt(
    const bf16* __restrict__ Abase, const bf16* __restrict__ Btbase,
    const float* __restrict__ bias, float* __restrict__ xres,
    bf16* __restrict__ outb_,
    int M, int N, int K, int lda, int ldb, int ldc) {
  constexpr int MI = WM / 16, NI = WN / 16;
  constexpr int NWN = BN / WN;
  const int tid = threadIdx.x;
  const int lane = tid & 63, wave = tid >> 6;
  const int wm = (wave / NWN) * WM, wn = (wave % NWN) * WN;
  const int tm0 = blockIdx.x * BM, tn0 = blockIdx.y * BN;
  const int z = blockIdx.z;

  const bf16* A = Abase;
  const bf16* Bt = Btbase;
  bf16* outb = outb_;

  if (MODE == 4) {
    A = Abase + (size_t)z * Nc * Nc;          // bf16 attn copy (ws)
    Bt = Btbase + (size_t)z * DHc * Nc;       // V^T per (b,h)
    outb = outb_ + (size_t)(z / Hc) * Nc * Dc + (size_t)(z % Hc) * DHc;
  }

  __shared__ __align__(16) bf16 As[2][BM * 32];
  __shared__ __align__(16) bf16 Bs[2][BN * 32];

  f32x4 acc[MI][NI] = {};

  const int nt = K >> 5;  // K/32 steps

  // stage tile t into buffer buf
  auto stage = [&](int buf, int k0) {
    #pragma unroll
    for (int rr = 0; rr < BM / 64; rr++) {
      int e = rr * 2048 + tid * 8;
      int r = e >> 5, kk = e & 31;
      gload16(A + (size_t)(tm0 + r) * lda + (k0 + kk), &As[buf][e]);
    }
    #pragma unroll
    for (int rr = 0; rr < BN / 64; rr++) {
      int e = rr * 2048 + tid * 8;
      int r = e >> 5, kk = e & 31;
      gload16(Bt + (size_t)(tn0 + r) * ldb + (k0 + kk), &Bs[buf][e]);
    }
  };

  stage(0, 0);
  __syncthreads();

  int cur = 0;
  for (int kt = 0; kt < nt; kt++) {
    if (kt + 1 < nt) stage(cur ^ 1, (kt + 1) * 32);  // prefetch next tile

    b16x8 af[MI], bfr[NI];
    #pragma unroll
    for (int i = 0; i < MI; i++)
      af[i] = *(const b16x8*)(&As[cur][(wm + i * 16 + (lane & 15)) * 32 + (lane >> 4) * 8]);
    #pragma unroll
    for (int j = 0; j < NI; j++)
      bfr[j] = *(const b16x8*)(&Bs[cur][(wn + j * 16 + (lane & 15)) * 32 + (lane >> 4) * 8]);
    #pragma unroll
    for (int i = 0; i < MI; i++)
      #pragma unroll
      for (int j = 0; j < NI; j++)
        mfma_bf16(acc[i][j], af[i], bfr[j]);

    __syncthreads();  // drains vmcnt (prefetch done) + all waves done reading cur
    cur ^= 1;
  }

  // epilogue: D mapping col = lane&15, row = (lane>>4)*4 + reg
  const int r0 = (lane >> 4) * 4;
  const int c0 = lane & 15;
  #pragma unroll
  for (int i = 0; i < MI; i++) {
    #pragma unroll
    for (int j = 0; j < NI; j++) {
      #pragma unroll
      for (int r = 0; r < 4; r++) {
        int row = tm0 + wm + i * 16 + r0 + r;
        int col = tn0 + wn + j * 16 + c0;
        float v = acc[i][j][r];
        if (MODE == 0) {
          outb[(size_t)row * ldc + col] = f2b(v);
        } else if (MODE == 1) {
          v += bias[col];
          float g = 0.5f * v * (1.0f + erff(v * 0.70710678118654752f));
          outb[(size_t)row * ldc + col] = f2b(g);
        } else if (MODE == 2) {
          v += bias[col];
          xres[(size_t)row * ldc + col] += v;
        } else {  // MODE 4
          outb[(size_t)row * ldc + col] = f2b(v);
        }
      }
    }
  }
}

// ---------------------------------------------------------------------------
// Fused QK^T * SCALE -> softmax. One block = 32 q-rows x all 512 kv for one
// (b,h). K-head staged once in LDS (padded rows: kills 128B-stride bank
// conflicts). Softmax entirely in-register on the MFMA accumulators.
// Writes fp32 attn to d_out and bf16 copy for the PV GEMM.
// ---------------------------------------------------------------------------
__global__ __launch_bounds__(256) void qksm_k(const bf16* __restrict__ qkv,
                                              float* __restrict__ attn_f,
                                              bf16* __restrict__ attn_b) {
  const int bh = blockIdx.y;
  const int b = bh / Hc, h = bh % Hc;
  const int n0 = blockIdx.x * 32;
  const int tid = threadIdx.x, lane = tid & 63, wave = tid >> 6;
  const int wn = wave * 128;

  constexpr int KP = 72;  // 64 + 8 pad (bank-conflict break, keeps 16B align)
  __shared__ __align__(16) bf16 Ks[512 * KP];
  __shared__ float red[32][4];

  const bf16* qbase = qkv + (size_t)b * Nc * QKVc + h * DHc;  // Q cols
  const bf16* kbase = qbase + Dc;                             // K cols

  // stage whole K-head: 512 rows x 64 cols
  for (int e = tid * 8; e < 512 * 64; e += 256 * 8) {
    int kv = e >> 6, c = e & 63;
    *(uint4*)(Ks + kv * KP + c) = *(const uint4*)(kbase + (size_t)kv * QKVc + c);
  }
  // Q fragments direct from global
  b16x8 qf[2][2];  // [ks][i]
  #pragma unroll
  for (int ks = 0; ks < 2; ks++)
    #pragma unroll
    for (int i = 0; i < 2; i++)
      qf[ks][i] = *(const b16x8*)(qbase +
          (size_t)(n0 + i * 16 + (lane & 15)) * QKVc + ks * 32 + (lane >> 4) * 8);
  __syncthreads();

  f32x4 acc[2][8] = {};  // [i(row16)][j(col16)]
  #pragma unroll
  for (int ks = 0; ks < 2; ks++) {
    #pragma unroll
    for (int j = 0; j < 8; j++) {
      b16x8 kf = *(const b16x8*)(Ks + (wn + j * 16 + (lane & 15)) * KP +
                                 ks * 32 + (lane >> 4) * 8);
      #pragma unroll
      for (int i = 0; i < 2; i++)
        mfma_bf16(acc[i][j], qf[ks][i], kf);
    }
  }

  #pragma unroll
  for (int i = 0; i < 2; i++)
    #pragma unroll
    for (int j = 0; j < 8; j++)
      acc[i][j] *= SCALE;

  const int r0 = (lane >> 4) * 4, c0 = lane & 15;
  float rmax[2][4];
  #pragma unroll
  for (int i = 0; i < 2; i++)
    #pragma unroll
    for (int rr = 0; rr < 4; rr++) {
      float m = -1e30f;
      #pragma unroll
      for (int j = 0; j < 8; j++) m = fmaxf(m, acc[i][j][rr]);
      #pragma unroll
      for (int o = 1; o < 16; o <<= 1) m = fmaxf(m, __shfl_xor(m, o));
      rmax[i][rr] = m;
    }
  if (c0 == 0) {
    #pragma unroll
    for (int i = 0; i < 2; i++)
      #pragma unroll
      for (int rr = 0; rr < 4; rr++)
        red[i * 16 + r0 + rr][wave] = rmax[i][rr];
  }
  __syncthreads();
  #pragma unroll
  for (int i = 0; i < 2; i++)
    #pragma unroll
    for (int rr = 0; rr < 4; rr++) {
      int r = i * 16 + r0 + rr;
      rmax[i][rr] = fmaxf(fmaxf(red[r][0], red[r][1]), fmaxf(red[r][2], red[r][3]));
    }
  __syncthreads();  // red reused for sums

  float rsum[2][4];
  #pragma unroll
  for (int i = 0; i < 2; i++)
    #pragma unroll
    for (int rr = 0; rr < 4; rr++) {
      float s = 0.f;
      #pragma unroll
      for (int j = 0; j < 8; j++) {
        float e = expf(acc[i][j][rr] - rmax[i][rr]);
        acc[i][j][rr] = e;
        s += e;
      }
      #pragma unroll
      for (int o = 1; o < 16; o <<= 1) s += __shfl_xor(s, o);
      rsum[i][rr] = s;
    }
  if (c0 == 0) {
    #pragma unroll
    for (int i = 0; i < 2; i++)
      #pragma unroll
      for (int rr = 0; rr < 4; rr++)
        red[i * 16 + r0 + rr][wave] = rsum[i][rr];
  }
  __syncthreads();
  #pragma unroll
  for (int i = 0; i < 2; i++)
    #pragma unroll
    for (int rr = 0; rr < 4; rr++) {
      int r = i * 16 + r0 + rr;
      rsum[i][rr] = 1.0f / (red[r][0] + red[r][1] + red[r][2] + red[r][3]);
    }

  float* of = attn_f + (size_t)bh * Nc * Nc;
  bf16*  ob = attn_b + (size_t)bh * Nc * Nc;
  #pragma unroll
  for (int i = 0; i < 2; i++)
    #pragma unroll
    for (int j = 0; j < 8; j++)
      #pragma unroll
      for (int rr = 0; rr < 4; rr++) {
        int row = n0 + i * 16 + r0 + rr;
        int col = wn + j * 16 + c0;
        float p = acc[i][j][rr] * rsum[i][rr];
        of[(size_t)row * Nc + col] = p;
        ob[(size_t)row * Nc + col] = f2b(p);
      }
}

// ---------------------------------------------------------------------------
// LayerNorm: per row of 768, fp32 in -> bf16 out
// ---------------------------------------------------------------------------
__global__ __launch_bounds__(256) void ln_k(const float* __restrict__ x,
                                            const float* __restrict__ s,
                                            const float* __restrict__ b,
                                            bf16* __restrict__ out) {
  const int row = blockIdx.x, tid = threadIdx.x;
  const float* xr = x + (size_t)row * Dc;
  float a0 = xr[tid], a1 = xr[tid + 256], a2 = xr[tid + 512];
  float sum = a0 + a1 + a2;
  float sq = a0 * a0 + a1 * a1 + a2 * a2;
  #pragma unroll
  for (int o = 32; o; o >>= 1) {
    sum += __shfl_down(sum, o);
    sq += __shfl_down(sq, o);
  }
  __shared__ float s1[4], s2[4];
  if ((tid & 63) == 0) { s1[tid >> 6] = sum; s2[tid >> 6] = sq; }
  __syncthreads();
  sum = s1[0] + s1[1] + s1[2] + s1[3];
  sq = s2[0] + s2[1] + s2[2] + s2[3];
  float m = sum * (1.0f / Dc);
  float var = sq * (1.0f / Dc) - m * m;
  float rs = rsqrtf(var + 1e-5f);
  bf16* orow = out + (size_t)row * Dc;
  orow[tid]       = f2b((a0 - m) * rs * s[tid]       + b[tid]);
  orow[tid + 256] = f2b((a1 - m) * rs * s[tid + 256] + b[tid + 256]);
  orow[tid + 512] = f2b((a2 - m) * rs * s[tid + 512] + b[tid + 512]);
}

// ---------------------------------------------------------------------------
// Weight transpose + fp32->bf16:  out[n][k] = bf16(in[k][n]); dims % 64 == 0
// ---------------------------------------------------------------------------
__global__ __launch_bounds__(256) void twb_k(const float* __restrict__ in,
                                             bf16* __restrict__ out, int K, int Nw) {
  const int n0 = blockIdx.x * 64, k0 = blockIdx.y * 64;
  __shared__ bf16 t[64][65];
  const int tx = threadIdx.x & 63, ty = threadIdx.x >> 6;
  #pragma unroll
  for (int kk = ty; kk < 64; kk += 4)
    t[tx][kk] = f2b(in[(size_t)(k0 + kk) * Nw + n0 + tx]);
  __syncthreads();
  #pragma unroll
  for (int nn = ty; nn < 64; nn += 4)
    out[(size_t)(n0 + nn) * K + k0 + tx] = t[nn][tx];
}

// ---------------------------------------------------------------------------
// V transpose: vt[(b*H+h)*64 + d][n] = qkv[(b*512+n)][1536 + h*64 + d]
// ---------------------------------------------------------------------------
__global__ __launch_bounds__(256) void vtrans_k(const bf16* __restrict__ qkv,
                                                bf16* __restrict__ vt) {
  const int bh = blockIdx.z;
  const int b = bh / Hc, h = bh % Hc;
  const int n0 = blockIdx.x * 64;
  const bf16* src = qkv + (size_t)b * Nc * QKVc + 2 * Dc + h * DHc;
  __shared__ bf16 t[64][65];
  const int tx = threadIdx.x & 63, ty = threadIdx.x >> 6;
  #pragma unroll
  for (int nn = ty; nn < 64; nn += 4)
    t[tx][nn] = src[(size_t)(n0 + nn) * QKVc + tx];
  __syncthreads();
  bf16* dst = vt + (size_t)bh * DHc * Nc;
  #pragma unroll
  for (int dd = ty; dd < 64; dd += 4)
    dst[(size_t)dd * Nc + n0 + tx] = t[dd][tx];
}

// ---------------------------------------------------------------------------
extern "C" void kernel_launch(void* const* d_in, const int* in_sizes, int n_in,
                              void* d_out, int out_size, void* d_ws, size_t ws_size,
                              hipStream_t stream) {
  const float* x_in  = (const float*)d_in[0];
  const float* ln1_s = (const float*)d_in[1];
  const float* ln1_b = (const float*)d_in[2];
  const float* wqkv  = (const float*)d_in[3];
  const float* wo    = (const float*)d_in[4];
  const float* bo    = (const float*)d_in[5];
  const float* ln2_s = (const float*)d_in[6];
  const float* ln2_b = (const float*)d_in[7];
  const float* w1    = (const float*)d_in[8];
  const float* b1    = (const float*)d_in[9];
  const float* w2    = (const float*)d_in[10];
  const float* b2    = (const float*)d_in[11];
  float* out = (float*)d_out;   // fp32 (reference outputs are float32)

  // workspace carve-up (bytes)
  char* ws = (char*)d_ws;
  float* x      = (float*)(ws + 0);          //  6,291,456  fp32 [2048][768]
  bf16* h       = (bf16*)(ws + 6291456);     //  3,145,728  bf16 [2048][768]
  bf16* qkv     = (bf16*)(ws + 9437184);     //  9,437,184  bf16 [2048][2304]
  bf16* o       = (bf16*)(ws + 18874368);    //  3,145,728  bf16 [2048][768]
  bf16* ff      = (bf16*)(ws + 22020096);    // 12,582,912  bf16 [2048][3072]
  bf16* vt      = (bf16*)(ws + 34603008);    //  3,145,728  bf16 [48][64][512]
  bf16* wT      = (bf16*)(ws + 37748736);    //  4,718,592  bf16 (max of the 4 W^T)
  bf16* attn_bf = (bf16*)(ws + 42467328);    // 25,165,824  bf16 [48][512][512]
  if (ws_size < (size_t)67633152) return;

  hipMemcpyAsync(x, x_in, (size_t)Mrows * Dc * sizeof(float),
                 hipMemcpyDeviceToDevice, stream);

  constexpr size_t ATTN_BASE = (size_t)Mrows * Dc;           // floats
  constexpr size_t ATTN_L = (size_t)Bc * Hc * Nc * Nc;       // floats

  for (int l = 0; l < Lc; l++) {
    float* attn_l = out + ATTN_BASE + (size_t)l * ATTN_L;    // fp32 slice

    // --- attention ---
    twb_k<<<dim3(QKVc / 64, Dc / 64), 256, 0, stream>>>(
        wqkv + (size_t)l * Dc * QKVc, wT, Dc, QKVc);
    ln_k<<<Mrows, 256, 0, stream>>>(x, ln1_s + l * Dc, ln1_b + l * Dc, h);
    gemm_bt<128, 128, 64, 64, 0><<<dim3(Mrows / 128, QKVc / 128, 1), 256, 0, stream>>>(
        h, wT, nullptr, nullptr, qkv, Mrows, QKVc, Dc, Dc, Dc, QKVc);
    vtrans_k<<<dim3(Nc / 64, 1, Bc * Hc), 256, 0, stream>>>(qkv, vt);
    // fused QK^T*scale + softmax -> fp32 attn (d_out) + bf16 copy (ws)
    qksm_k<<<dim3(Nc / 32, Bc * Hc), 256, 0, stream>>>(qkv, attn_l, attn_bf);
    gemm_bt<128, 64, 64, 32, 4><<<dim3(Nc / 128, 1, Bc * Hc), 256, 0, stream>>>(
        attn_bf, vt, nullptr, nullptr, o, Nc, DHc, Nc, Nc, Nc, Dc);
    twb_k<<<dim3(Dc / 64, Dc / 64), 256, 0, stream>>>(
        wo + (size_t)l * Dc * Dc, wT, Dc, Dc);
    // o-proj: BN=64 -> 192 blocks (was 96)
    gemm_bt<128, 64, 64, 32, 2><<<dim3(Mrows / 128, Dc / 64, 1), 256, 0, stream>>>(
        o, wT, bo + l * Dc, x, nullptr, Mrows, Dc, Dc, Dc, Dc, Dc);

    // --- feed-forward ---
    ln_k<<<Mrows, 256, 0, stream>>>(x, ln2_s + l * Dc, ln2_b + l * Dc, h);
    twb_k<<<dim3(DFFc / 64, Dc / 64), 256, 0, stream>>>(
        w1 + (size_t)l * Dc * DFFc, wT, Dc, DFFc);
    gemm_bt<128, 128, 64, 64, 1><<<dim3(Mrows / 128, DFFc / 128, 1), 256, 0, stream>>>(
        h, wT, b1 + l * DFFc, nullptr, ff, Mrows, DFFc, Dc, Dc, Dc, DFFc);
    twb_k<<<dim3(Dc / 64, DFFc / 64), 256, 0, stream>>>(
        w2 + (size_t)l * DFFc * Dc, wT, DFFc, Dc);
    // ff2: K=3072, BN=64 -> 192 blocks (was 96)
    gemm_bt<128, 64, 64, 32, 2><<<dim3(Mrows / 128, Dc / 64, 1), 256, 0, stream>>>(
        ff, wT, b2 + l * Dc, x, nullptr, Mrows, Dc, DFFc, DFFc, DFFc, Dc);
  }

  // final residual stream -> d_out (fp32)
  hipMemcpyAsync(out, x, (size_t)Mrows * Dc * sizeof(float),
                 hipMemcpyDeviceToDevice, stream);
}

// Round 7
// 2120.372 us; speedup vs baseline: 1.8442x; 1.1774x over previous
//
#include <hip/hip_runtime.h>
#include <hip/hip_bf16.h>

typedef __hip_bfloat16 bf16;
typedef float f32x4 __attribute__((ext_vector_type(4)));
typedef __bf16 b16x8 __attribute__((ext_vector_type(8)));

constexpr int Lc = 12, Bc = 4, Nc = 512, Dc = 768, Hc = 12, DHc = 64, DFFc = 3072;
constexpr int QKVc = 3 * Dc;          // 2304
constexpr int Mrows = Bc * Nc;        // 2048
constexpr float SCALE = 0.125f;       // 1/sqrt(64)

__device__ __forceinline__ bf16 f2b(float x) { return __float2bfloat16(x); }

__device__ __forceinline__ void mfma_bf16(f32x4& d, b16x8 a, b16x8 b) {
  d = __builtin_amdgcn_mfma_f32_16x16x32_bf16(a, b, d, 0, 0, 0);
}

// async global->LDS, 16B per lane. LDS dest must be linear (wave base + lane*16).
__device__ __forceinline__ void gload16(const bf16* g, bf16* l) {
  __builtin_amdgcn_global_load_lds(
      (const __attribute__((address_space(1))) void*)g,
      (__attribute__((address_space(3))) void*)l, 16, 0, 0);
}

// ---------------------------------------------------------------------------
// Generic GEMM:  C[m][n] = sum_k A[m][k] * Bt[n][k]   (A, Bt bf16 row-major)
// 2-phase double-buffered K-loop (prefetch next tile before computing cur).
// MODE 0: outb = bf16(C)                      (qkv projection, no bias)
// MODE 1: outb = bf16(gelu(C + bias))         (ff1)
// MODE 2: xres += C + bias; SPLITK>1 -> atomicAdd partials (bias on slice 0)
// MODE 4: outb = bf16(C), per-(b,h) ptrs      (PV, A = bf16 attn copy)
// ---------------------------------------------------------------------------
template <int BM, int BN, int WM, int WN, int MODE, int SPLITK = 1>
__global__ __launch_bounds__(256) void gemm_bt(
    const bf16* __restrict__ Abase, const bf16* __restrict__ Btbase,
    const float* __restrict__ bias, float* __restrict__ xres,
    bf16* __restrict__ outb_,
    int M, int N, int K, int lda, int ldb, int ldc) {
  constexpr int MI = WM / 16, NI = WN / 16;
  constexpr int NWN = BN / WN;
  const int tid = threadIdx.x;
  const int lane = tid & 63, wave = tid >> 6;
  const int wm = (wave / NWN) * WM, wn = (wave % NWN) * WN;
  const int tm0 = blockIdx.x * BM, tn0 = blockIdx.y * BN;
  const int z = blockIdx.z;

  const bf16* A = Abase;
  const bf16* Bt = Btbase;
  bf16* outb = outb_;

  if (MODE == 4) {
    A = Abase + (size_t)z * Nc * Nc;          // bf16 attn copy (ws)
    Bt = Btbase + (size_t)z * DHc * Nc;       // V^T per (b,h)
    outb = outb_ + (size_t)(z / Hc) * Nc * Dc + (size_t)(z % Hc) * DHc;
  }

  // split-K range (MODE 2 only)
  const int Kslice = K / SPLITK;
  const int kbase = (SPLITK > 1) ? z * Kslice : 0;

  __shared__ __align__(16) bf16 As[2][BM * 32];
  __shared__ __align__(16) bf16 Bs[2][BN * 32];

  f32x4 acc[MI][NI] = {};

  const int nt = Kslice >> 5;

  auto stage = [&](int buf, int k0) {
    #pragma unroll
    for (int rr = 0; rr < BM / 64; rr++) {
      int e = rr * 2048 + tid * 8;
      int r = e >> 5, kk = e & 31;
      gload16(A + (size_t)(tm0 + r) * lda + (kbase + k0 + kk), &As[buf][e]);
    }
    #pragma unroll
    for (int rr = 0; rr < BN / 64; rr++) {
      int e = rr * 2048 + tid * 8;
      int r = e >> 5, kk = e & 31;
      gload16(Bt + (size_t)(tn0 + r) * ldb + (kbase + k0 + kk), &Bs[buf][e]);
    }
  };

  stage(0, 0);
  __syncthreads();

  int cur = 0;
  for (int kt = 0; kt < nt; kt++) {
    if (kt + 1 < nt) stage(cur ^ 1, (kt + 1) * 32);

    b16x8 af[MI], bfr[NI];
    #pragma unroll
    for (int i = 0; i < MI; i++)
      af[i] = *(const b16x8*)(&As[cur][(wm + i * 16 + (lane & 15)) * 32 + (lane >> 4) * 8]);
    #pragma unroll
    for (int j = 0; j < NI; j++)
      bfr[j] = *(const b16x8*)(&Bs[cur][(wn + j * 16 + (lane & 15)) * 32 + (lane >> 4) * 8]);
    #pragma unroll
    for (int i = 0; i < MI; i++)
      #pragma unroll
      for (int j = 0; j < NI; j++)
        mfma_bf16(acc[i][j], af[i], bfr[j]);

    __syncthreads();
    cur ^= 1;
  }

  // epilogue: D mapping col = lane&15, row = (lane>>4)*4 + reg
  const int r0 = (lane >> 4) * 4;
  const int c0 = lane & 15;
  #pragma unroll
  for (int i = 0; i < MI; i++) {
    #pragma unroll
    for (int j = 0; j < NI; j++) {
      #pragma unroll
      for (int r = 0; r < 4; r++) {
        int row = tm0 + wm + i * 16 + r0 + r;
        int col = tn0 + wn + j * 16 + c0;
        float v = acc[i][j][r];
        if (MODE == 0) {
          outb[(size_t)row * ldc + col] = f2b(v);
        } else if (MODE == 1) {
          v += bias[col];
          float g = 0.5f * v * (1.0f + erff(v * 0.70710678118654752f));
          outb[(size_t)row * ldc + col] = f2b(g);
        } else if (MODE == 2) {
          if (SPLITK > 1) {
            if (z == 0) v += bias[col];
            atomicAdd(&xres[(size_t)row * ldc + col], v);
          } else {
            v += bias[col];
            xres[(size_t)row * ldc + col] += v;
          }
        } else {  // MODE 4
          outb[(size_t)row * ldc + col] = f2b(v);
        }
      }
    }
  }
}

// ---------------------------------------------------------------------------
// Fused QK^T * SCALE -> softmax. One block = 32 q-rows x all 512 kv for one
// (b,h). Softmax in-register on the MFMA accumulators.
// Writes fp32 attn to d_out and bf16 copy for the PV GEMM.
// ---------------------------------------------------------------------------
__global__ __launch_bounds__(256) void qksm_k(const bf16* __restrict__ qkv,
                                              float* __restrict__ attn_f,
                                              bf16* __restrict__ attn_b) {
  const int bh = blockIdx.y;
  const int b = bh / Hc, h = bh % Hc;
  const int n0 = blockIdx.x * 32;
  const int tid = threadIdx.x, lane = tid & 63, wave = tid >> 6;
  const int wn = wave * 128;

  constexpr int KP = 72;  // 64 + 8 pad
  __shared__ __align__(16) bf16 Ks[512 * KP];
  __shared__ float red[32][4];

  const bf16* qbase = qkv + (size_t)b * Nc * QKVc + h * DHc;  // Q cols
  const bf16* kbase = qbase + Dc;                             // K cols

  for (int e = tid * 8; e < 512 * 64; e += 256 * 8) {
    int kv = e >> 6, c = e & 63;
    *(uint4*)(Ks + kv * KP + c) = *(const uint4*)(kbase + (size_t)kv * QKVc + c);
  }
  b16x8 qf[2][2];  // [ks][i]
  #pragma unroll
  for (int ks = 0; ks < 2; ks++)
    #pragma unroll
    for (int i = 0; i < 2; i++)
      qf[ks][i] = *(const b16x8*)(qbase +
          (size_t)(n0 + i * 16 + (lane & 15)) * QKVc + ks * 32 + (lane >> 4) * 8);
  __syncthreads();

  f32x4 acc[2][8] = {};
  #pragma unroll
  for (int ks = 0; ks < 2; ks++) {
    #pragma unroll
    for (int j = 0; j < 8; j++) {
      b16x8 kf = *(const b16x8*)(Ks + (wn + j * 16 + (lane & 15)) * KP +
                                 ks * 32 + (lane >> 4) * 8);
      #pragma unroll
      for (int i = 0; i < 2; i++)
        mfma_bf16(acc[i][j], qf[ks][i], kf);
    }
  }

  #pragma unroll
  for (int i = 0; i < 2; i++)
    #pragma unroll
    for (int j = 0; j < 8; j++)
      acc[i][j] *= SCALE;

  const int r0 = (lane >> 4) * 4, c0 = lane & 15;
  float rmax[2][4];
  #pragma unroll
  for (int i = 0; i < 2; i++)
    #pragma unroll
    for (int rr = 0; rr < 4; rr++) {
      float m = -1e30f;
      #pragma unroll
      for (int j = 0; j < 8; j++) m = fmaxf(m, acc[i][j][rr]);
      #pragma unroll
      for (int o = 1; o < 16; o <<= 1) m = fmaxf(m, __shfl_xor(m, o));
      rmax[i][rr] = m;
    }
  if (c0 == 0) {
    #pragma unroll
    for (int i = 0; i < 2; i++)
      #pragma unroll
      for (int rr = 0; rr < 4; rr++)
        red[i * 16 + r0 + rr][wave] = rmax[i][rr];
  }
  __syncthreads();
  #pragma unroll
  for (int i = 0; i < 2; i++)
    #pragma unroll
    for (int rr = 0; rr < 4; rr++) {
      int r = i * 16 + r0 + rr;
      rmax[i][rr] = fmaxf(fmaxf(red[r][0], red[r][1]), fmaxf(red[r][2], red[r][3]));
    }
  __syncthreads();

  float rsum[2][4];
  #pragma unroll
  for (int i = 0; i < 2; i++)
    #pragma unroll
    for (int rr = 0; rr < 4; rr++) {
      float s = 0.f;
      #pragma unroll
      for (int j = 0; j < 8; j++) {
        float e = expf(acc[i][j][rr] - rmax[i][rr]);
        acc[i][j][rr] = e;
        s += e;
      }
      #pragma unroll
      for (int o = 1; o < 16; o <<= 1) s += __shfl_xor(s, o);
      rsum[i][rr] = s;
    }
  if (c0 == 0) {
    #pragma unroll
    for (int i = 0; i < 2; i++)
      #pragma unroll
      for (int rr = 0; rr < 4; rr++)
        red[i * 16 + r0 + rr][wave] = rsum[i][rr];
  }
  __syncthreads();
  #pragma unroll
  for (int i = 0; i < 2; i++)
    #pragma unroll
    for (int rr = 0; rr < 4; rr++) {
      int r = i * 16 + r0 + rr;
      rsum[i][rr] = 1.0f / (red[r][0] + red[r][1] + red[r][2] + red[r][3]);
    }

  float* of = attn_f + (size_t)bh * Nc * Nc;
  bf16*  ob = attn_b + (size_t)bh * Nc * Nc;
  #pragma unroll
  for (int i = 0; i < 2; i++)
    #pragma unroll
    for (int j = 0; j < 8; j++)
      #pragma unroll
      for (int rr = 0; rr < 4; rr++) {
        int row = n0 + i * 16 + r0 + rr;
        int col = wn + j * 16 + c0;
        float p = acc[i][j][rr] * rsum[i][rr];
        of[(size_t)row * Nc + col] = p;
        ob[(size_t)row * Nc + col] = f2b(p);
      }
}

// ---------------------------------------------------------------------------
// LayerNorm: per row of 768, fp32 in -> bf16 out
// ---------------------------------------------------------------------------
__global__ __launch_bounds__(256) void ln_k(const float* __restrict__ x,
                                            const float* __restrict__ s,
                                            const float* __restrict__ b,
                                            bf16* __restrict__ out) {
  const int row = blockIdx.x, tid = threadIdx.x;
  const float* xr = x + (size_t)row * Dc;
  float a0 = xr[tid], a1 = xr[tid + 256], a2 = xr[tid + 512];
  float sum = a0 + a1 + a2;
  float sq = a0 * a0 + a1 * a1 + a2 * a2;
  #pragma unroll
  for (int o = 32; o; o >>= 1) {
    sum += __shfl_down(sum, o);
    sq += __shfl_down(sq, o);
  }
  __shared__ float s1[4], s2[4];
  if ((tid & 63) == 0) { s1[tid >> 6] = sum; s2[tid >> 6] = sq; }
  __syncthreads();
  sum = s1[0] + s1[1] + s1[2] + s1[3];
  sq = s2[0] + s2[1] + s2[2] + s2[3];
  float m = sum * (1.0f / Dc);
  float var = sq * (1.0f / Dc) - m * m;
  float rs = rsqrtf(var + 1e-5f);
  bf16* orow = out + (size_t)row * Dc;
  orow[tid]       = f2b((a0 - m) * rs * s[tid]       + b[tid]);
  orow[tid + 256] = f2b((a1 - m) * rs * s[tid + 256] + b[tid + 256]);
  orow[tid + 512] = f2b((a2 - m) * rs * s[tid + 512] + b[tid + 512]);
}

// ---------------------------------------------------------------------------
// Batched weight transpose+convert for all 4 weights of one layer.
// flat tile ranges: [0,432) qkv | [432,576) wo | [576,1152) w1 | [1152,1728) w2
// ---------------------------------------------------------------------------
__global__ __launch_bounds__(256) void twb_all_k(
    const float* __restrict__ wqkv_l, const float* __restrict__ wo_l,
    const float* __restrict__ w1_l, const float* __restrict__ w2_l,
    bf16* __restrict__ wTq, bf16* __restrict__ wTo,
    bf16* __restrict__ wT1, bf16* __restrict__ wT2) {
  int f = blockIdx.x;
  const float* in;
  bf16* outp;
  int K, Nw, n0, k0;
  if (f < 432)       { in = wqkv_l; outp = wTq; K = Dc;   Nw = QKVc; n0 = (f % 36) * 64; k0 = (f / 36) * 64; }
  else if (f < 576)  { f -= 432;  in = wo_l; outp = wTo; K = Dc;   Nw = Dc;   n0 = (f % 12) * 64; k0 = (f / 12) * 64; }
  else if (f < 1152) { f -= 576;  in = w1_l; outp = wT1; K = Dc;   Nw = DFFc; n0 = (f % 48) * 64; k0 = (f / 48) * 64; }
  else               { f -= 1152; in = w2_l; outp = wT2; K = DFFc; Nw = Dc;   n0 = (f % 12) * 64; k0 = (f / 12) * 64; }

  __shared__ bf16 t[64][65];
  const int tx = threadIdx.x & 63, ty = threadIdx.x >> 6;
  #pragma unroll
  for (int kk = ty; kk < 64; kk += 4)
    t[tx][kk] = f2b(in[(size_t)(k0 + kk) * Nw + n0 + tx]);
  __syncthreads();
  #pragma unroll
  for (int nn = ty; nn < 64; nn += 4)
    outp[(size_t)(n0 + nn) * K + k0 + tx] = t[nn][tx];
}

// ---------------------------------------------------------------------------
// V transpose: vt[(b*H+h)*64 + d][n] = qkv[(b*512+n)][1536 + h*64 + d]
// ---------------------------------------------------------------------------
__global__ __launch_bounds__(256) void vtrans_k(const bf16* __restrict__ qkv,
                                                bf16* __restrict__ vt) {
  const int bh = blockIdx.z;
  const int b = bh / Hc, h = bh % Hc;
  const int n0 = blockIdx.x * 64;
  const bf16* src = qkv + (size_t)b * Nc * QKVc + 2 * Dc + h * DHc;
  __shared__ bf16 t[64][65];
  const int tx = threadIdx.x & 63, ty = threadIdx.x >> 6;
  #pragma unroll
  for (int nn = ty; nn < 64; nn += 4)
    t[tx][nn] = src[(size_t)(n0 + nn) * QKVc + tx];
  __syncthreads();
  bf16* dst = vt + (size_t)bh * DHc * Nc;
  #pragma unroll
  for (int dd = ty; dd < 64; dd += 4)
    dst[(size_t)dd * Nc + n0 + tx] = t[dd][tx];
}

// ---------------------------------------------------------------------------
extern "C" void kernel_launch(void* const* d_in, const int* in_sizes, int n_in,
                              void* d_out, int out_size, void* d_ws, size_t ws_size,
                              hipStream_t stream) {
  const float* x_in  = (const float*)d_in[0];
  const float* ln1_s = (const float*)d_in[1];
  const float* ln1_b = (const float*)d_in[2];
  const float* wqkv  = (const float*)d_in[3];
  const float* wo    = (const float*)d_in[4];
  const float* bo    = (const float*)d_in[5];
  const float* ln2_s = (const float*)d_in[6];
  const float* ln2_b = (const float*)d_in[7];
  const float* w1    = (const float*)d_in[8];
  const float* b1    = (const float*)d_in[9];
  const float* w2    = (const float*)d_in[10];
  const float* b2    = (const float*)d_in[11];
  float* out = (float*)d_out;   // fp32 (reference outputs are float32)

  // workspace carve-up (bytes)
  char* ws = (char*)d_ws;
  float* x      = (float*)(ws + 0);          //  6,291,456  fp32 [2048][768]
  bf16* h       = (bf16*)(ws + 6291456);     //  3,145,728
  bf16* qkv     = (bf16*)(ws + 9437184);     //  9,437,184
  bf16* o       = (bf16*)(ws + 18874368);    //  3,145,728
  bf16* ff      = (bf16*)(ws + 22020096);    // 12,582,912
  bf16* vt      = (bf16*)(ws + 34603008);    //  3,145,728
  bf16* wTq     = (bf16*)(ws + 37748736);    //  3,538,944  [2304][768]
  bf16* wTo     = (bf16*)(ws + 41287680);    //  1,179,648  [768][768]
  bf16* wT1     = (bf16*)(ws + 42467328);    //  4,718,592  [3072][768]
  bf16* wT2     = (bf16*)(ws + 47185920);    //  4,718,592  [768][3072]
  bf16* attn_bf = (bf16*)(ws + 51904512);    // 25,165,824  [48][512][512]
  if (ws_size < (size_t)77070336) return;

  hipMemcpyAsync(x, x_in, (size_t)Mrows * Dc * sizeof(float),
                 hipMemcpyDeviceToDevice, stream);

  constexpr size_t ATTN_BASE = (size_t)Mrows * Dc;           // floats
  constexpr size_t ATTN_L = (size_t)Bc * Hc * Nc * Nc;       // floats

  for (int l = 0; l < Lc; l++) {
    float* attn_l = out + ATTN_BASE + (size_t)l * ATTN_L;    // fp32 slice

    // all 4 weight transposes in one launch
    twb_all_k<<<1728, 256, 0, stream>>>(
        wqkv + (size_t)l * Dc * QKVc, wo + (size_t)l * Dc * Dc,
        w1 + (size_t)l * Dc * DFFc, w2 + (size_t)l * DFFc * Dc,
        wTq, wTo, wT1, wT2);

    // --- attention ---
    ln_k<<<Mrows, 256, 0, stream>>>(x, ln1_s + l * Dc, ln1_b + l * Dc, h);
    gemm_bt<128, 128, 64, 64, 0><<<dim3(Mrows / 128, QKVc / 128, 1), 256, 0, stream>>>(
        h, wTq, nullptr, nullptr, qkv, Mrows, QKVc, Dc, Dc, Dc, QKVc);
    vtrans_k<<<dim3(Nc / 64, 1, Bc * Hc), 256, 0, stream>>>(qkv, vt);
    qksm_k<<<dim3(Nc / 32, Bc * Hc), 256, 0, stream>>>(qkv, attn_l, attn_bf);
    gemm_bt<64, 64, 32, 32, 4><<<dim3(Nc / 64, 1, Bc * Hc), 256, 0, stream>>>(
        attn_bf, vt, nullptr, nullptr, o, Nc, DHc, Nc, Nc, Nc, Dc);
    // o-proj: split-K x2 -> 384 blocks
    gemm_bt<128, 64, 64, 32, 2, 2><<<dim3(Mrows / 128, Dc / 64, 2), 256, 0, stream>>>(
        o, wTo, bo + l * Dc, x, nullptr, Mrows, Dc, Dc, Dc, Dc, Dc);

    // --- feed-forward ---
    ln_k<<<Mrows, 256, 0, stream>>>(x, ln2_s + l * Dc, ln2_b + l * Dc, h);
    gemm_bt<128, 128, 64, 64, 1><<<dim3(Mrows / 128, DFFc / 128, 1), 256, 0, stream>>>(
        h, wT1, b1 + l * DFFc, nullptr, ff, Mrows, DFFc, Dc, Dc, Dc, DFFc);
    // ff2: split-K x4 -> 768 blocks, 24 K-steps each
    gemm_bt<128, 64, 64, 32, 2, 4><<<dim3(Mrows / 128, Dc / 64, 4), 256, 0, stream>>>(
        ff, wT2, b2 + l * Dc, x, nullptr, Mrows, Dc, DFFc, DFFc, DFFc, Dc);
  }

  // final residual stream -> d_out (fp32)
  hipMemcpyAsync(out, x, (size_t)Mrows * Dc * sizeof(float),
                 hipMemcpyDeviceToDevice, stream);
}